// Round 1
// baseline (3505.069 us; speedup 1.0000x reference)
//
#include <hip/hip_runtime.h>
#include <math.h>

#define BLK 256
#define PPT 2   // points per thread

// Level resolutions: floor(16 * 1.5^l) = 16, 24, 36, 54. Levels 0,1 dense; 2,3 hashed.
// grid layout: [4][32768][4] float.

__global__ __launch_bounds__(BLK) void ngp_fused_kernel(
    const float* __restrict__ dirs,
    const float* __restrict__ grid,
    const float* __restrict__ W1, const float* __restrict__ b1,
    const float* __restrict__ W2, const float* __restrict__ b2,
    const float* __restrict__ W3, const float* __restrict__ b3,
    const float* __restrict__ W4, const float* __restrict__ b4,
    float* __restrict__ out, int n)
{
    __shared__ __align__(16) float sW1[16 * 32];
    __shared__ __align__(16) float sW2[32 * 16];
    __shared__ __align__(16) float sW3[16 * 8];
    __shared__ __align__(16) float sW4[8 * 3];
    __shared__ __align__(16) float sb1[32];
    __shared__ __align__(16) float sb2[16];
    __shared__ __align__(16) float sb3[8];
    __shared__ __align__(16) float sb4[4];

    const int t = threadIdx.x;
    for (int i = t; i < 512; i += BLK) { sW1[i] = W1[i]; sW2[i] = W2[i]; }
    if (t < 128) sW3[t] = W3[t];
    if (t < 24)  sW4[t] = W4[t];
    if (t < 32)  sb1[t] = b1[t];
    if (t < 16)  sb2[t] = b2[t];
    if (t < 8)   sb3[t] = b3[t];
    if (t < 3)   sb4[t] = b4[t];
    __syncthreads();

    const int base = blockIdx.x * (BLK * PPT);

    float feats[PPT][16];
    int   pid[PPT];
    bool  ok[PPT];

    // ---------------- hash-grid encode ----------------
    #pragma unroll
    for (int k = 0; k < PPT; k++) {
        int i = base + k * BLK + t;
        pid[k] = i;
        ok[k] = (i < n);
        int j = ok[k] ? i : 0;
        float dx = dirs[3 * j + 0];
        float dy = dirs[3 * j + 1];
        float dz = dirs[3 * j + 2];

        #pragma unroll
        for (int l = 0; l < 4; l++) {
            const int res = (l == 0) ? 16 : (l == 1) ? 24 : (l == 2) ? 36 : 54;
            float px = dx * (float)res, py = dy * (float)res, pz = dz * (float)res;
            float fpx = floorf(px), fpy = floorf(py), fpz = floorf(pz);
            float fx = px - fpx, fy = py - fpy, fz = pz - fpz;
            int x0 = (int)fpx, y0 = (int)fpy, z0 = (int)fpz;

            float a0 = 0.f, a1 = 0.f, a2 = 0.f, a3 = 0.f;
            #pragma unroll
            for (int c = 0; c < 8; c++) {
                const int ci = (c >> 2) & 1;   // x offset (CORNERS outer loop is i -> dim 0)
                const int cj = (c >> 1) & 1;   // y offset
                const int ck = c & 1;          // z offset
                int gx = x0 + ci; gx = gx > res ? res : (gx < 0 ? 0 : gx);
                int gy = y0 + cj; gy = gy > res ? res : (gy < 0 ? 0 : gy);
                int gz = z0 + ck; gz = gz > res ? res : (gz < 0 ? 0 : gz);
                unsigned int idx;
                if (l < 2) {
                    idx = (unsigned int)(gx + (res + 1) * (gy + (res + 1) * gz));
                } else {
                    idx = ((unsigned int)gx
                         ^ ((unsigned int)gy * 2654435761u)
                         ^ ((unsigned int)gz * 805459861u)) & 32767u;
                }
                float w = (ci ? fx : 1.0f - fx)
                        * (cj ? fy : 1.0f - fy)
                        * (ck ? fz : 1.0f - fz);
                const float4 v = *reinterpret_cast<const float4*>(
                    grid + (((unsigned int)l << 15) + idx) * 4u);
                a0 += w * v.x; a1 += w * v.y; a2 += w * v.z; a3 += w * v.w;
            }
            feats[k][4 * l + 0] = a0;
            feats[k][4 * l + 1] = a1;
            feats[k][4 * l + 2] = a2;
            feats[k][4 * l + 3] = a3;
        }
    }

    // ---------------- MLP: 16 -> 32 -> 16 -> 8 -> 3 ----------------
    float h1[PPT][32];
    #pragma unroll
    for (int j = 0; j < 32; j++) {
        float b = sb1[j];
        #pragma unroll
        for (int k = 0; k < PPT; k++) h1[k][j] = b;
    }
    #pragma unroll
    for (int i = 0; i < 16; i++) {
        #pragma unroll
        for (int j = 0; j < 32; j += 4) {
            float4 w = *reinterpret_cast<const float4*>(&sW1[i * 32 + j]);
            #pragma unroll
            for (int k = 0; k < PPT; k++) {
                float f = feats[k][i];
                h1[k][j + 0] += f * w.x;
                h1[k][j + 1] += f * w.y;
                h1[k][j + 2] += f * w.z;
                h1[k][j + 3] += f * w.w;
            }
        }
    }
    #pragma unroll
    for (int j = 0; j < 32; j++)
        #pragma unroll
        for (int k = 0; k < PPT; k++)
            h1[k][j] = fmaxf(h1[k][j], 0.2f * h1[k][j]);

    float h2[PPT][16];
    #pragma unroll
    for (int j = 0; j < 16; j++) {
        float b = sb2[j];
        #pragma unroll
        for (int k = 0; k < PPT; k++) h2[k][j] = b;
    }
    #pragma unroll
    for (int i = 0; i < 32; i++) {
        #pragma unroll
        for (int j = 0; j < 16; j += 4) {
            float4 w = *reinterpret_cast<const float4*>(&sW2[i * 16 + j]);
            #pragma unroll
            for (int k = 0; k < PPT; k++) {
                float f = h1[k][i];
                h2[k][j + 0] += f * w.x;
                h2[k][j + 1] += f * w.y;
                h2[k][j + 2] += f * w.z;
                h2[k][j + 3] += f * w.w;
            }
        }
    }
    #pragma unroll
    for (int j = 0; j < 16; j++)
        #pragma unroll
        for (int k = 0; k < PPT; k++)
            h2[k][j] = fmaxf(h2[k][j], 0.2f * h2[k][j]);

    float h3[PPT][8];
    #pragma unroll
    for (int j = 0; j < 8; j++) {
        float b = sb3[j];
        #pragma unroll
        for (int k = 0; k < PPT; k++) h3[k][j] = b;
    }
    #pragma unroll
    for (int i = 0; i < 16; i++) {
        #pragma unroll
        for (int j = 0; j < 8; j += 4) {
            float4 w = *reinterpret_cast<const float4*>(&sW3[i * 8 + j]);
            #pragma unroll
            for (int k = 0; k < PPT; k++) {
                float f = h2[k][i];
                h3[k][j + 0] += f * w.x;
                h3[k][j + 1] += f * w.y;
                h3[k][j + 2] += f * w.z;
                h3[k][j + 3] += f * w.w;
            }
        }
    }
    #pragma unroll
    for (int j = 0; j < 8; j++)
        #pragma unroll
        for (int k = 0; k < PPT; k++)
            h3[k][j] = fmaxf(h3[k][j], 0.2f * h3[k][j]);

    float o[PPT][3];
    #pragma unroll
    for (int j = 0; j < 3; j++) {
        float b = sb4[j];
        #pragma unroll
        for (int k = 0; k < PPT; k++) o[k][j] = b;
    }
    #pragma unroll
    for (int i = 0; i < 8; i++) {
        #pragma unroll
        for (int j = 0; j < 3; j++) {
            float w = sW4[i * 3 + j];
            #pragma unroll
            for (int k = 0; k < PPT; k++) o[k][j] += h3[k][i] * w;
        }
    }

    #pragma unroll
    for (int k = 0; k < PPT; k++) {
        if (ok[k]) {
            int i = pid[k];
            out[3 * i + 0] = tanhf(o[k][0]);
            out[3 * i + 1] = tanhf(o[k][1]);
            out[3 * i + 2] = tanhf(o[k][2]);
        }
    }
}

extern "C" void kernel_launch(void* const* d_in, const int* in_sizes, int n_in,
                              void* d_out, int out_size, void* d_ws, size_t ws_size,
                              hipStream_t stream) {
    const float* dirs = (const float*)d_in[0];
    const float* grid = (const float*)d_in[1];
    const float* W1 = (const float*)d_in[2];
    const float* b1 = (const float*)d_in[3];
    const float* W2 = (const float*)d_in[4];
    const float* b2 = (const float*)d_in[5];
    const float* W3 = (const float*)d_in[6];
    const float* b3 = (const float*)d_in[7];
    const float* W4 = (const float*)d_in[8];
    const float* b4 = (const float*)d_in[9];
    float* out = (float*)d_out;

    const int n = in_sizes[0] / 3;
    const int pts_per_block = BLK * PPT;
    const int nblocks = (n + pts_per_block - 1) / pts_per_block;

    hipLaunchKernelGGL(ngp_fused_kernel, dim3(nblocks), dim3(BLK), 0, stream,
                       dirs, grid, W1, b1, W2, b2, W3, b3, W4, b4, out, n);
}

// Round 2
// 245.744 us; speedup vs baseline: 14.2631x; 14.2631x over previous
//
#include <hip/hip_runtime.h>
#include <math.h>

#define BLK 256

// Level resolutions: floor(16 * 1.5^l) = 16, 24, 36, 54. Levels 0,1 dense; 2,3 hashed.
// grid layout: [4][32768][4] float. Weights staged in LDS (broadcast reads).

__global__ __launch_bounds__(BLK, 4) void ngp_fused_kernel(
    const float* __restrict__ dirs,
    const float* __restrict__ grid,
    const float* __restrict__ W1, const float* __restrict__ b1,
    const float* __restrict__ W2, const float* __restrict__ b2,
    const float* __restrict__ W3, const float* __restrict__ b3,
    const float* __restrict__ W4, const float* __restrict__ b4,
    float* __restrict__ out, int n)
{
    __shared__ __align__(16) float sW1[16 * 32];
    __shared__ __align__(16) float sW2[32 * 16];
    __shared__ __align__(16) float sW3[16 * 8];
    __shared__ __align__(16) float sW4[8 * 3];
    __shared__ __align__(16) float sb1[32];
    __shared__ __align__(16) float sb2[16];
    __shared__ __align__(16) float sb3[8];
    __shared__ __align__(16) float sb4[4];

    const int t = threadIdx.x;
    for (int i = t; i < 512; i += BLK) { sW1[i] = W1[i]; sW2[i] = W2[i]; }
    if (t < 128) sW3[t] = W3[t];
    if (t < 24)  sW4[t] = W4[t];
    if (t < 32)  sb1[t] = b1[t];
    if (t < 16)  sb2[t] = b2[t];
    if (t < 8)   sb3[t] = b3[t];
    if (t < 3)   sb4[t] = b4[t];
    __syncthreads();

    const int i = blockIdx.x * BLK + t;
    const bool ok = (i < n);
    const int j = ok ? i : 0;

    const float dx = dirs[3 * j + 0];
    const float dy = dirs[3 * j + 1];
    const float dz = dirs[3 * j + 2];

    // ---------------- hash-grid encode ----------------
    float feats[16];
    #pragma unroll
    for (int l = 0; l < 4; l++) {
        const int res = (l == 0) ? 16 : (l == 1) ? 24 : (l == 2) ? 36 : 54;
        float px = dx * (float)res, py = dy * (float)res, pz = dz * (float)res;
        float fpx = floorf(px), fpy = floorf(py), fpz = floorf(pz);
        float fx = px - fpx, fy = py - fpy, fz = pz - fpz;
        int x0 = (int)fpx, y0 = (int)fpy, z0 = (int)fpz;

        float a0 = 0.f, a1 = 0.f, a2 = 0.f, a3 = 0.f;
        #pragma unroll
        for (int c = 0; c < 8; c++) {
            const int ci = (c >> 2) & 1;   // x offset
            const int cj = (c >> 1) & 1;   // y offset
            const int ck = c & 1;          // z offset
            int gx = x0 + ci; gx = gx > res ? res : (gx < 0 ? 0 : gx);
            int gy = y0 + cj; gy = gy > res ? res : (gy < 0 ? 0 : gy);
            int gz = z0 + ck; gz = gz > res ? res : (gz < 0 ? 0 : gz);
            unsigned int idx;
            if (l < 2) {
                idx = (unsigned int)(gx + (res + 1) * (gy + (res + 1) * gz));
            } else {
                idx = ((unsigned int)gx
                     ^ ((unsigned int)gy * 2654435761u)
                     ^ ((unsigned int)gz * 805459861u)) & 32767u;
            }
            float w = (ci ? fx : 1.0f - fx)
                    * (cj ? fy : 1.0f - fy)
                    * (ck ? fz : 1.0f - fz);
            const float4 v = *reinterpret_cast<const float4*>(
                grid + (((unsigned int)l << 15) + idx) * 4u);
            a0 += w * v.x; a1 += w * v.y; a2 += w * v.z; a3 += w * v.w;
        }
        feats[4 * l + 0] = a0;
        feats[4 * l + 1] = a1;
        feats[4 * l + 2] = a2;
        feats[4 * l + 3] = a3;
    }

    // ---------------- MLP: 16 -> 32 -> 16 -> 8 -> 3 ----------------
    float h1[32];
    #pragma unroll
    for (int jj = 0; jj < 32; jj++) h1[jj] = sb1[jj];
    #pragma unroll
    for (int ii = 0; ii < 16; ii++) {
        const float f = feats[ii];
        #pragma unroll
        for (int jj = 0; jj < 32; jj += 4) {
            float4 w = *reinterpret_cast<const float4*>(&sW1[ii * 32 + jj]);
            h1[jj + 0] += f * w.x;
            h1[jj + 1] += f * w.y;
            h1[jj + 2] += f * w.z;
            h1[jj + 3] += f * w.w;
        }
    }
    #pragma unroll
    for (int jj = 0; jj < 32; jj++) h1[jj] = fmaxf(h1[jj], 0.2f * h1[jj]);

    float h2[16];
    #pragma unroll
    for (int jj = 0; jj < 16; jj++) h2[jj] = sb2[jj];
    #pragma unroll
    for (int ii = 0; ii < 32; ii++) {
        const float f = h1[ii];
        #pragma unroll
        for (int jj = 0; jj < 16; jj += 4) {
            float4 w = *reinterpret_cast<const float4*>(&sW2[ii * 16 + jj]);
            h2[jj + 0] += f * w.x;
            h2[jj + 1] += f * w.y;
            h2[jj + 2] += f * w.z;
            h2[jj + 3] += f * w.w;
        }
    }
    #pragma unroll
    for (int jj = 0; jj < 16; jj++) h2[jj] = fmaxf(h2[jj], 0.2f * h2[jj]);

    float h3[8];
    #pragma unroll
    for (int jj = 0; jj < 8; jj++) h3[jj] = sb3[jj];
    #pragma unroll
    for (int ii = 0; ii < 16; ii++) {
        const float f = h2[ii];
        #pragma unroll
        for (int jj = 0; jj < 8; jj += 4) {
            float4 w = *reinterpret_cast<const float4*>(&sW3[ii * 8 + jj]);
            h3[jj + 0] += f * w.x;
            h3[jj + 1] += f * w.y;
            h3[jj + 2] += f * w.z;
            h3[jj + 3] += f * w.w;
        }
    }
    #pragma unroll
    for (int jj = 0; jj < 8; jj++) h3[jj] = fmaxf(h3[jj], 0.2f * h3[jj]);

    float o0 = sb4[0], o1 = sb4[1], o2 = sb4[2];
    #pragma unroll
    for (int ii = 0; ii < 8; ii++) {
        const float f = h3[ii];
        o0 += f * sW4[ii * 3 + 0];
        o1 += f * sW4[ii * 3 + 1];
        o2 += f * sW4[ii * 3 + 2];
    }

    if (ok) {
        out[3 * i + 0] = tanhf(o0);
        out[3 * i + 1] = tanhf(o1);
        out[3 * i + 2] = tanhf(o2);
    }
}

extern "C" void kernel_launch(void* const* d_in, const int* in_sizes, int n_in,
                              void* d_out, int out_size, void* d_ws, size_t ws_size,
                              hipStream_t stream) {
    const float* dirs = (const float*)d_in[0];
    const float* grid = (const float*)d_in[1];
    const float* W1 = (const float*)d_in[2];
    const float* b1 = (const float*)d_in[3];
    const float* W2 = (const float*)d_in[4];
    const float* b2 = (const float*)d_in[5];
    const float* W3 = (const float*)d_in[6];
    const float* b3 = (const float*)d_in[7];
    const float* W4 = (const float*)d_in[8];
    const float* b4 = (const float*)d_in[9];
    float* out = (float*)d_out;

    const int n = in_sizes[0] / 3;
    const int nblocks = (n + BLK - 1) / BLK;

    hipLaunchKernelGGL(ngp_fused_kernel, dim3(nblocks), dim3(BLK), 0, stream,
                       dirs, grid, W1, b1, W2, b2, W3, b3, W4, b4, out, n);
}

// Round 3
// 188.179 us; speedup vs baseline: 18.6263x; 1.3059x over previous
//
#include <hip/hip_runtime.h>
#include <hip/hip_fp16.h>
#include <math.h>

#define BLK 256

typedef float f2 __attribute__((ext_vector_type(2)));
typedef unsigned int uint;
typedef unsigned int uint4v __attribute__((ext_vector_type(4), aligned(8))); // 16B load, 8B-aligned
typedef unsigned int uint2v __attribute__((ext_vector_type(2)));             // 8B load

__device__ __forceinline__ f2 cvt2(uint u) {
    __half2 h = *reinterpret_cast<__half2*>(&u);
    return (f2){ __low2float(h), __high2float(h) };
}

__device__ __forceinline__ f2 leaky2(f2 x) {
    return (f2){ fmaxf(x[0], 0.2f * x[0]), fmaxf(x[1], 0.2f * x[1]) };
}

// grid fp32 layout: [4][32768][4]. fp16 repack: same layout, 8B/entry.
__global__ __launch_bounds__(256) void repack_kernel(const float* __restrict__ g,
                                                     __half* __restrict__ h) {
    const int i = blockIdx.x * 256 + threadIdx.x;   // groups of 4 floats; 131072 total
    float4 v = reinterpret_cast<const float4*>(g)[i];
    __half2 h0 = __floats2half2_rn(v.x, v.y);
    __half2 h1 = __floats2half2_rn(v.z, v.w);
    uint2 u;
    u.x = *reinterpret_cast<uint*>(&h0);
    u.y = *reinterpret_cast<uint*>(&h1);
    reinterpret_cast<uint2*>(h)[i] = u;
}

template<int F16>
__global__ __launch_bounds__(BLK, 3) void ngp_fused(
    const float* __restrict__ dirs,
    const float* __restrict__ grid32,
    const __half* __restrict__ grid16,
    const float* __restrict__ W1, const float* __restrict__ b1,
    const float* __restrict__ W2, const float* __restrict__ b2,
    const float* __restrict__ W3, const float* __restrict__ b3,
    const float* __restrict__ W4, const float* __restrict__ b4,
    float* __restrict__ out, int n)
{
    __shared__ __align__(16) float sW1[16 * 32];
    __shared__ __align__(16) float sW2[32 * 16];
    __shared__ __align__(16) float sW3[16 * 8];
    __shared__ __align__(16) float sW4[8 * 3];
    __shared__ __align__(16) float sb1[32];
    __shared__ __align__(16) float sb2[16];
    __shared__ __align__(16) float sb3[8];
    __shared__ __align__(16) float sb4[4];

    const int t = threadIdx.x;
    for (int q = t; q < 512; q += BLK) { sW1[q] = W1[q]; sW2[q] = W2[q]; }
    if (t < 128) sW3[t] = W3[t];
    if (t < 24)  sW4[t] = W4[t];
    if (t < 32)  sb1[t] = b1[t];
    if (t < 16)  sb2[t] = b2[t];
    if (t < 8)   sb3[t] = b3[t];
    if (t < 3)   sb4[t] = b4[t];
    __syncthreads();

    const int i = blockIdx.x * BLK + t;
    const bool ok = (i < n);
    const int j = ok ? i : 0;

    const float dx = dirs[3 * j + 0];
    const float dy = dirs[3 * j + 1];
    const float dz = dirs[3 * j + 2];

    f2 fe01[4], fe23[4];   // per-level feats: (f0,f1) and (f2,f3)

    #pragma unroll
    for (int l = 0; l < 4; l++) {
        const int res = (l == 0) ? 16 : (l == 1) ? 24 : (l == 2) ? 36 : 54;
        const int R1 = res + 1;
        float px = dx * (float)res, py = dy * (float)res, pz = dz * (float)res;
        float fpx = floorf(px), fpy = floorf(py), fpz = floorf(pz);
        float fx = px - fpx, fy = py - fpy, fz = pz - fpz;
        int x0 = (int)fpx, y0 = (int)fpy, z0 = (int)fpz;
        int x0c = min(max(x0, 0), res), x1c = min(max(x0 + 1, 0), res);
        int y0c = min(max(y0, 0), res), y1c = min(max(y0 + 1, 0), res);
        int z0c = min(max(z0, 0), res), z1c = min(max(z0 + 1, 0), res);
        float wx0 = 1.f - fx, wx1 = fx;
        float wy0 = 1.f - fy, wy1 = fy, wz0 = 1.f - fz, wz1 = fz;
        float wyz[4] = { wy0 * wz0, wy0 * wz1, wy1 * wz0, wy1 * wz1 }; // q=(cj<<1)|ck

        f2 a01 = (f2)(0.f), a23 = (f2)(0.f);

        if (l < 2) {
            // dense: idx = x + R1*(y + R1*z); x-pairs contiguous
            uint bo[4];
            bo[0] = (uint)(R1 * (y0c + R1 * z0c));
            bo[1] = (uint)(R1 * (y0c + R1 * z1c));
            bo[2] = (uint)(R1 * (y1c + R1 * z0c));
            bo[3] = (uint)(R1 * (y1c + R1 * z1c));
            if (F16) {
                // fold x-clamp into weights: if x1c==x0c both corners are same entry
                const bool xdup = (x1c == x0c);
                const float ex0 = xdup ? (wx0 + wx1) : wx0;
                const float ex1 = xdup ? 0.f : wx1;
                const char* base = (const char*)grid16 + (size_t)l * 262144;
                uint4v v[4];
                #pragma unroll
                for (int q = 0; q < 4; q++)
                    v[q] = *reinterpret_cast<const uint4v*>(
                        base + (size_t)(bo[q] + (uint)x0c) * 8u);
                #pragma unroll
                for (int q = 0; q < 4; q++) {
                    const float w0 = ex0 * wyz[q], w1 = ex1 * wyz[q];
                    a01 += w0 * cvt2(v[q].x) + w1 * cvt2(v[q].z);
                    a23 += w0 * cvt2(v[q].y) + w1 * cvt2(v[q].w);
                }
            } else {
                const float* base = grid32 + (size_t)l * 131072;
                float4 v[8];
                #pragma unroll
                for (int c = 0; c < 8; c++) {
                    uint idx = ((c & 4) ? (uint)x1c : (uint)x0c) + bo[c & 3];
                    v[c] = *reinterpret_cast<const float4*>(base + idx * 4u);
                }
                #pragma unroll
                for (int c = 0; c < 8; c++) {
                    const float w = ((c & 4) ? wx1 : wx0) * wyz[c & 3];
                    a01 += w * (f2){ v[c].x, v[c].y };
                    a23 += w * (f2){ v[c].z, v[c].w };
                }
            }
        } else {
            // hashed: (x ^ y*p1 ^ z*p2) & 32767
            const uint ty0 = (uint)y0c * 2654435761u, ty1 = (uint)y1c * 2654435761u;
            const uint tz0 = (uint)z0c * 805459861u,  tz1 = (uint)z1c * 805459861u;
            const uint hx0 = (uint)x0c, hx1 = (uint)x1c;
            uint idx[8];
            idx[0] = (hx0 ^ ty0 ^ tz0) & 32767u;
            idx[1] = (hx0 ^ ty0 ^ tz1) & 32767u;
            idx[2] = (hx0 ^ ty1 ^ tz0) & 32767u;
            idx[3] = (hx0 ^ ty1 ^ tz1) & 32767u;
            idx[4] = (hx1 ^ ty0 ^ tz0) & 32767u;
            idx[5] = (hx1 ^ ty0 ^ tz1) & 32767u;
            idx[6] = (hx1 ^ ty1 ^ tz0) & 32767u;
            idx[7] = (hx1 ^ ty1 ^ tz1) & 32767u;
            if (F16) {
                const char* base = (const char*)grid16 + (size_t)l * 262144;
                uint2v v[8];
                #pragma unroll
                for (int c = 0; c < 8; c++)
                    v[c] = *reinterpret_cast<const uint2v*>(base + (size_t)idx[c] * 8u);
                #pragma unroll
                for (int c = 0; c < 8; c++) {
                    const float w = ((c & 4) ? wx1 : wx0) * wyz[c & 3];
                    a01 += w * cvt2(v[c].x);
                    a23 += w * cvt2(v[c].y);
                }
            } else {
                const float* base = grid32 + (size_t)l * 131072;
                float4 v[8];
                #pragma unroll
                for (int c = 0; c < 8; c++)
                    v[c] = *reinterpret_cast<const float4*>(base + idx[c] * 4u);
                #pragma unroll
                for (int c = 0; c < 8; c++) {
                    const float w = ((c & 4) ? wx1 : wx0) * wyz[c & 3];
                    a01 += w * (f2){ v[c].x, v[c].y };
                    a23 += w * (f2){ v[c].z, v[c].w };
                }
            }
        }
        fe01[l] = a01;
        fe23[l] = a23;
    }

    float fs[16];
    #pragma unroll
    for (int l = 0; l < 4; l++) {
        fs[4 * l + 0] = fe01[l][0];
        fs[4 * l + 1] = fe01[l][1];
        fs[4 * l + 2] = fe23[l][0];
        fs[4 * l + 3] = fe23[l][1];
    }

    // ---------------- MLP (packed f2 math) ----------------
    f2 a1[16];
    #pragma unroll
    for (int jj = 0; jj < 16; jj++) a1[jj] = *reinterpret_cast<const f2*>(&sb1[2 * jj]);
    #pragma unroll
    for (int ii = 0; ii < 16; ii++) {
        const float f = fs[ii];
        #pragma unroll
        for (int jj = 0; jj < 8; jj++) {
            float4 w4 = *reinterpret_cast<const float4*>(&sW1[ii * 32 + 4 * jj]);
            a1[2 * jj + 0] += f * (f2){ w4.x, w4.y };
            a1[2 * jj + 1] += f * (f2){ w4.z, w4.w };
        }
    }
    #pragma unroll
    for (int jj = 0; jj < 16; jj++) a1[jj] = leaky2(a1[jj]);

    f2 a2[8];
    #pragma unroll
    for (int jj = 0; jj < 8; jj++) a2[jj] = *reinterpret_cast<const f2*>(&sb2[2 * jj]);
    #pragma unroll
    for (int ii = 0; ii < 32; ii++) {
        const float f = a1[ii >> 1][ii & 1];
        #pragma unroll
        for (int jj = 0; jj < 4; jj++) {
            float4 w4 = *reinterpret_cast<const float4*>(&sW2[ii * 16 + 4 * jj]);
            a2[2 * jj + 0] += f * (f2){ w4.x, w4.y };
            a2[2 * jj + 1] += f * (f2){ w4.z, w4.w };
        }
    }
    #pragma unroll
    for (int jj = 0; jj < 8; jj++) a2[jj] = leaky2(a2[jj]);

    f2 a3[4];
    #pragma unroll
    for (int jj = 0; jj < 4; jj++) a3[jj] = *reinterpret_cast<const f2*>(&sb3[2 * jj]);
    #pragma unroll
    for (int ii = 0; ii < 16; ii++) {
        const float f = a2[ii >> 1][ii & 1];
        #pragma unroll
        for (int jj = 0; jj < 2; jj++) {
            float4 w4 = *reinterpret_cast<const float4*>(&sW3[ii * 8 + 4 * jj]);
            a3[2 * jj + 0] += f * (f2){ w4.x, w4.y };
            a3[2 * jj + 1] += f * (f2){ w4.z, w4.w };
        }
    }
    #pragma unroll
    for (int jj = 0; jj < 4; jj++) a3[jj] = leaky2(a3[jj]);

    float o0 = sb4[0], o1 = sb4[1], o2 = sb4[2];
    #pragma unroll
    for (int ii = 0; ii < 8; ii++) {
        const float f = a3[ii >> 1][ii & 1];
        o0 += f * sW4[ii * 3 + 0];
        o1 += f * sW4[ii * 3 + 1];
        o2 += f * sW4[ii * 3 + 2];
    }

    if (ok) {
        out[3 * i + 0] = tanhf(o0);
        out[3 * i + 1] = tanhf(o1);
        out[3 * i + 2] = tanhf(o2);
    }
}

extern "C" void kernel_launch(void* const* d_in, const int* in_sizes, int n_in,
                              void* d_out, int out_size, void* d_ws, size_t ws_size,
                              hipStream_t stream) {
    const float* dirs = (const float*)d_in[0];
    const float* grid = (const float*)d_in[1];
    const float* W1 = (const float*)d_in[2];
    const float* b1 = (const float*)d_in[3];
    const float* W2 = (const float*)d_in[4];
    const float* b2 = (const float*)d_in[5];
    const float* W3 = (const float*)d_in[6];
    const float* b3 = (const float*)d_in[7];
    const float* W4 = (const float*)d_in[8];
    const float* b4 = (const float*)d_in[9];
    float* out = (float*)d_out;

    const int n = in_sizes[0] / 3;
    const int nblocks = (n + BLK - 1) / BLK;
    const size_t need16 = (size_t)4 * 32768 * 4 * sizeof(__half);   // 1 MiB

    if (ws_size >= need16) {
        // grid elements = 524288 -> 131072 float4 groups -> 512 blocks
        hipLaunchKernelGGL(repack_kernel, dim3(512), dim3(256), 0, stream,
                           grid, (__half*)d_ws);
        hipLaunchKernelGGL((ngp_fused<1>), dim3(nblocks), dim3(BLK), 0, stream,
                           dirs, grid, (const __half*)d_ws,
                           W1, b1, W2, b2, W3, b3, W4, b4, out, n);
    } else {
        hipLaunchKernelGGL((ngp_fused<0>), dim3(nblocks), dim3(BLK), 0, stream,
                           dirs, grid, (const __half*)nullptr,
                           W1, b1, W2, b2, W3, b3, W4, b4, out, n);
    }
}